// Round 1
// baseline (1316.016 us; speedup 1.0000x reference)
//
#include <hip/hip_runtime.h>
#include <cstdint>

typedef unsigned short u16;
typedef __bf16 bf8 __attribute__((ext_vector_type(8)));
typedef float f4 __attribute__((ext_vector_type(4)));
typedef u16 u16x4 __attribute__((ext_vector_type(4)));

#define NB 16
#define CH 256
#define HH 64
#define HP 66
#define KTOT 2304
#define SCALE (1.0f/48.0f)

// output offsets (floats) in d_out: out(16,3,512,512), flow, delta_flow, flow
#define OFF1 12582912
#define OFF2 20971520
#define OFF3 29360128

__device__ __forceinline__ unsigned bf16_rn(unsigned u) {
  return (u + 0x7fffu + ((u >> 16) & 1u)) >> 16;
}
__device__ __forceinline__ void split2(float x, u16 &h, u16 &l) {
  unsigned u = __float_as_uint(x);
  unsigned hb = bf16_rn(u);
  float hf = __uint_as_float(hb << 16);
  unsigned lb = bf16_rn(__float_as_uint(x - hf));
  h = (u16)hb; l = (u16)lb;
}

// async global->LDS, 16B per lane; lds pointer must be wave-uniform
__device__ __forceinline__ void g2l16(const void* g, void* l) {
  __builtin_amdgcn_global_load_lds(
      (__attribute__((address_space(1))) void*)(uintptr_t)g,
      (__attribute__((address_space(3))) void*)(uint32_t)(uintptr_t)l,
      16, 0, 0);
}

// ---------------- repack features: NCHW fp32 -> padded [n][66][66][ci] bf16 hi/lo
__global__ void repack_feat(const float* __restrict__ f, u16* __restrict__ hi,
                            u16* __restrict__ lo) {
  __shared__ float t[64][65];
  int ny = blockIdx.x; int n = ny >> 6, y = ny & 63;
  int ci0 = blockIdx.y << 6;
  int tid = threadIdx.x;
  int a = tid >> 6, bl = tid & 63;
  const float* src = f + (((size_t)n*CH + ci0)*HH + y)*HH;
  #pragma unroll
  for (int i = 0; i < 16; i++) {
    int ci = i*4 + a;
    t[ci][bl] = src[(size_t)ci*4096 + bl];
  }
  __syncthreads();
  size_t base = (((size_t)n*HP + (y+1))*HP + 1)*CH + ci0;
  #pragma unroll
  for (int i = 0; i < 16; i++) {
    int x = i*4 + a;
    float v = t[bl][x];
    u16 hv, lv; split2(v, hv, lv);
    hi[base + (size_t)x*CH + bl] = hv;
    lo[base + (size_t)x*CH + bl] = lv;
  }
}

// ---------------- repack weights: (Cout,256,3,3) -> A[co][t*256+ci] * 1/48, hi/lo
__global__ void repack_w(const float* __restrict__ w, u16* __restrict__ hi,
                         u16* __restrict__ lo, int Cout, int CoutPad) {
  int e = blockIdx.x*256 + threadIdx.x;
  if (e >= CoutPad*KTOT) return;
  int co = e / KTOT; int k = e - co*KTOT;
  int t = k >> 8, ci = k & 255;
  float v = 0.f;
  if (co < Cout) v = w[((size_t)co*CH + ci)*9 + t] * SCALE;
  u16 hv, lv; split2(v, hv, lv);
  hi[e] = hv; lo[e] = lv;
}

// ---------------- split-bf16 implicit-GEMM conv. 128x128 tile, BK=64.
// mode 0: h_pad fp32 relu(+bias)   mode 1: hm hi/lo bf16 relu(+bias)
// mode 2: mask fp32 (+bias), co<576
__global__ __launch_bounds__(256, 2) void conv_gemm(
    const u16* __restrict__ Ahi, const u16* __restrict__ Alo,
    const u16* __restrict__ Bhi, const u16* __restrict__ Blo,
    const float* __restrict__ bias,
    float* __restrict__ outF, u16* __restrict__ outHi, u16* __restrict__ outLo,
    int mode) {
  __shared__ u16 AsHi[8192], AsLo[8192], BsHi[8192], BsLo[8192];
  const int tid = threadIdx.x;
  const int wave = tid >> 6;
  const int lane = tid & 63;
  const int cb = blockIdx.x;
  const int mb = blockIdx.y;
  const int col0 = cb << 7;
  const int n = col0 >> 12;
  const int y0 = (col0 >> 6) & 63;

  // staging decomposition: seg(16 of 1KB) = wave*4+it; lane covers col=seg*8+(lane>>3),
  // 16B k-slot l=lane&7 holds swizzled k-segment g = l ^ (col&7)
  const int l8 = lane & 7;
  const int r8 = lane >> 3;
  const int gsg = l8 ^ r8;

  int aBase[4], bBase[4], segOf[4];
  #pragma unroll
  for (int it = 0; it < 4; ++it) {
    int seg = wave*4 + it;
    segOf[it] = seg*512;          // u16 elements = 1KB
    int rl = seg*8 + r8;          // rowLocal (A: co) / colLocal (B)
    aBase[it] = (mb*128 + rl)*KTOT + gsg*8;
    int yy = y0 + (rl >> 6);
    int xx = rl & 63;
    bBase[it] = ((n*HP + yy)*HP + xx)*CH + gsg*8;
  }

  const f4 zero = {0.f, 0.f, 0.f, 0.f};
  f4 acc[4][4];
  #pragma unroll
  for (int i = 0; i < 4; i++)
    #pragma unroll
    for (int j = 0; j < 4; j++) acc[i][j] = zero;

  const int wm = (wave >> 1) << 6;
  const int wn = (wave & 1) << 6;
  const int r16 = lane & 15;
  const int kg = lane >> 4;
  const int sw = lane & 7;

  for (int kc = 0; kc < 36; ++kc) {
    int t = kc >> 2;
    int ci0 = (kc & 3) << 6;
    int dy = t / 3;
    int dx = t - dy*3;
    int bOff = (dy*HP + dx)*CH + ci0;
    int aOff = kc << 6;
    #pragma unroll
    for (int it = 0; it < 4; ++it) {
      g2l16(Ahi + aBase[it] + aOff, AsHi + segOf[it]);
      g2l16(Alo + aBase[it] + aOff, AsLo + segOf[it]);
      g2l16(Bhi + bBase[it] + bOff, BsHi + segOf[it]);
      g2l16(Blo + bBase[it] + bOff, BsLo + segOf[it]);
    }
    __syncthreads();
    #pragma unroll
    for (int ks = 0; ks < 2; ++ks) {
      int slot = ((ks << 2) + kg) ^ sw;
      bf8 ahi[4], alo[4], bhi[4], blo[4];
      #pragma unroll
      for (int mi = 0; mi < 4; ++mi) {
        int idx = (wm + mi*16 + r16)*64 + slot*8;
        ahi[mi] = *(const bf8*)(AsHi + idx);
        alo[mi] = *(const bf8*)(AsLo + idx);
      }
      #pragma unroll
      for (int ni = 0; ni < 4; ++ni) {
        int idx = (wn + ni*16 + r16)*64 + slot*8;
        bhi[ni] = *(const bf8*)(BsHi + idx);
        blo[ni] = *(const bf8*)(BsLo + idx);
      }
      #pragma unroll
      for (int mi = 0; mi < 4; ++mi)
        #pragma unroll
        for (int ni = 0; ni < 4; ++ni) {
          acc[mi][ni] = __builtin_amdgcn_mfma_f32_16x16x32_bf16(ahi[mi], bhi[ni], acc[mi][ni], 0, 0, 0);
          acc[mi][ni] = __builtin_amdgcn_mfma_f32_16x16x32_bf16(ahi[mi], blo[ni], acc[mi][ni], 0, 0, 0);
          acc[mi][ni] = __builtin_amdgcn_mfma_f32_16x16x32_bf16(alo[mi], bhi[ni], acc[mi][ni], 0, 0, 0);
        }
    }
    __syncthreads();
  }

  // epilogue: C/D layout col=lane&15, row=(lane>>4)*4+reg  (row = co, col = spatial)
  const int g4 = kg << 2;
  #pragma unroll
  for (int mi = 0; mi < 4; ++mi) {
    int coB = mb*128 + wm + mi*16 + g4;
    bool valid = (mode != 2) || (coB < 576);
    f4 bv = zero;
    if (valid) bv = *(const f4*)(bias + coB);
    #pragma unroll
    for (int ni = 0; ni < 4; ++ni) {
      int col = col0 + wn + ni*16 + r16;
      f4 v = acc[mi][ni];
      #pragma unroll
      for (int q = 0; q < 4; q++) v[q] += bv[q];
      if (mode == 2) {
        if (valid) *(f4*)(outF + (size_t)col*576 + coB) = v;
      } else {
        #pragma unroll
        for (int q = 0; q < 4; q++) v[q] = fmaxf(v[q], 0.f);
        int nn = col >> 12, yy = (col >> 6) & 63, xx = col & 63;
        size_t addr = (((size_t)nn*HP + yy + 1)*HP + xx + 1)*CH + coB;
        if (mode == 0) {
          *(f4*)(outF + addr) = v;
        } else {
          u16x4 hv, lv;
          #pragma unroll
          for (int q = 0; q < 4; q++) { u16 a_, b_; split2(v[q], a_, b_); hv[q] = a_; lv[q] = b_; }
          *(u16x4*)(outHi + addr) = hv;
          *(u16x4*)(outLo + addr) = lv;
        }
      }
    }
  }
}

// ---------------- conv_f2: fp32 direct 256->2 from padded h
__global__ __launch_bounds__(256) void conv_f2(const float* __restrict__ hpad,
    const float* __restrict__ w2, const float* __restrict__ b2,
    float* __restrict__ flow) {
  __shared__ float ws[2*KTOT];
  int tid = threadIdx.x;
  for (int i = tid; i < 2*KTOT; i += 256) {
    int c = i / KTOT; int r = i - c*KTOT;
    int t = r >> 8, ci = r & 255;
    ws[i] = w2[((size_t)c*CH + ci)*9 + t] * SCALE;
  }
  __syncthreads();
  int ny = blockIdx.x; int n = ny >> 6, y = ny & 63;
  int wv = tid >> 6, lane = tid & 63;
  for (int p = 0; p < 16; p++) {
    int x = wv*16 + p;
    float s0 = 0.f, s1 = 0.f;
    #pragma unroll
    for (int t = 0; t < 9; t++) {
      int dy = t / 3, dx = t - dy*3;
      const float* hb = hpad + (((size_t)n*HP + y + dy)*HP + x + dx)*CH;
      const float* wa = ws + t*256;
      const float* wb = ws + KTOT + t*256;
      #pragma unroll
      for (int j = 0; j < 4; j++) {
        int ci = j*64 + lane;
        float v = hb[ci];
        s0 = fmaf(v, wa[ci], s0);
        s1 = fmaf(v, wb[ci], s1);
      }
    }
    #pragma unroll
    for (int o = 32; o; o >>= 1) { s0 += __shfl_xor(s0, o); s1 += __shfl_xor(s1, o); }
    if (lane == 0) {
      size_t col = (size_t)n*4096 + y*64 + x;
      flow[col*2]   = s0 + b2[0];
      flow[col*2+1] = s1 + b2[1];
    }
  }
}

// ---------------- fused: softmax(9) + convex upsample + grid + affine + bilinear sample
__global__ __launch_bounds__(256) void fuse_up(const float* __restrict__ mask,
    const float* __restrict__ flowlr, const float* __restrict__ img,
    const float* __restrict__ bwarp, float* __restrict__ out) {
  __shared__ float ms[4][576];
  __shared__ float fp[4][9][2];
  int tid = threadIdx.x;
  int cell = tid >> 6, lane = tid & 63;
  int b = blockIdx.x;
  int n = b >> 10;
  int h = (b >> 4) & 63;
  int w = ((b & 15) << 2) + cell;
  size_t col = (size_t)n*4096 + h*64 + w;
  #pragma unroll
  for (int r = 0; r < 9; r++) ms[cell][r*64 + lane] = mask[col*576 + r*64 + lane];
  if (lane < 18) {
    int k = lane >> 1, c = lane & 1;
    int hh = h + (k/3) - 1, ww = w + (k - (k/3)*3) - 1;
    float v = 0.f;
    if (hh >= 0 && hh < 64 && ww >= 0 && ww < 64)
      v = flowlr[(((size_t)n*4096) + hh*64 + ww)*2 + c];
    fp[cell][k][c] = 8.f * v;
  }
  __syncthreads();
  int u = lane >> 3, v = lane & 7;
  float mk[9]; float mx = -1e30f;
  #pragma unroll
  for (int k = 0; k < 9; k++) { mk[k] = ms[cell][k*64 + u*8 + v]; mx = fmaxf(mx, mk[k]); }
  float den = 0.f;
  #pragma unroll
  for (int k = 0; k < 9; k++) { mk[k] = __expf(mk[k] - mx); den += mk[k]; }
  float dxf = 0.f, dyf = 0.f;
  #pragma unroll
  for (int k = 0; k < 9; k++) { dxf += mk[k]*fp[cell][k][0]; dyf += mk[k]*fp[cell][k][1]; }
  dxf /= den; dyf /= den;
  int Y = h*8 + u, X = w*8 + v;
  float gx = (X + 0.5f)*(1.f/256.f) - 1.f;
  float gy = (Y + 0.5f)*(1.f/256.f) - 1.f;
  float fx = gx + dxf, fy = gy + dyf;
  const float* B = bwarp + n*6;
  float ax = B[0]*fx + B[1]*fy + B[2];
  float ay = B[3]*fx + B[4]*fy + B[5];
  size_t pix = (((size_t)n*512) + Y)*512 + X;
  *(float2*)(out + OFF1 + pix*2) = make_float2(ax, ay);
  *(float2*)(out + OFF2 + pix*2) = make_float2(dxf, dyf);
  *(float2*)(out + OFF3 + pix*2) = make_float2(ax, ay);
  float xs  = fminf(fmaxf((ax + 1.f)*256.f - 0.5f, 0.f), 511.f);
  float ysf = fminf(fmaxf((ay + 1.f)*256.f - 0.5f, 0.f), 511.f);
  float x0f = floorf(xs), y0f = floorf(ysf);
  int x0 = (int)x0f, y0 = (int)y0f;
  int x1 = min(x0 + 1, 511), y1 = min(y0 + 1, 511);
  float wx = xs - x0f, wy = ysf - y0f;
  #pragma unroll
  for (int c = 0; c < 3; c++) {
    const float* ip = img + ((size_t)(n*3 + c) << 18);
    float g00 = ip[y0*512 + x0], g01 = ip[y0*512 + x1];
    float g10 = ip[y1*512 + x0], g11 = ip[y1*512 + x1];
    float r = g00*(1.f-wx)*(1.f-wy) + g01*wx*(1.f-wy)
            + g10*(1.f-wx)*wy + g11*wx*wy;
    out[(((size_t)(n*3 + c))*512 + Y)*512 + X] = r;
  }
}

extern "C" void kernel_launch(void* const* d_in, const int* in_sizes, int n_in,
                              void* d_out, int out_size, void* d_ws, size_t ws_size,
                              hipStream_t stream) {
  const float* img   = (const float*)d_in[0];
  const float* feat  = (const float*)d_in[1];
  const float* bwarp = (const float*)d_in[2];
  const float* w_f1  = (const float*)d_in[3];
  const float* b_f1  = (const float*)d_in[4];
  const float* w_f2  = (const float*)d_in[5];
  const float* b_f2  = (const float*)d_in[6];
  const float* w_m1  = (const float*)d_in[7];
  const float* b_m1  = (const float*)d_in[8];
  const float* w_m2  = (const float*)d_in[9];
  const float* b_m2  = (const float*)d_in[10];
  float* out = (float*)d_out;

  char* ws = (char*)d_ws;
  size_t off = 0;
  auto alloc = [&](size_t bytes) -> char* {
    char* p = ws + off; off += (bytes + 255) & ~(size_t)255; return p;
  };
  const size_t NPAD = (size_t)NB*HP*HP*CH;   // 17,842,176
  u16* feat_hi = (u16*)alloc(NPAD*2);
  u16* feat_lo = (u16*)alloc(NPAD*2);
  float* h_pad = (float*)alloc(NPAD*4);
  u16* hm_hi   = (u16*)alloc(NPAD*2);
  u16* hm_lo   = (u16*)alloc(NPAD*2);
  u16* A1_hi   = (u16*)alloc((size_t)256*KTOT*2);
  u16* A1_lo   = (u16*)alloc((size_t)256*KTOT*2);
  u16* Am1_hi  = (u16*)alloc((size_t)256*KTOT*2);
  u16* Am1_lo  = (u16*)alloc((size_t)256*KTOT*2);
  u16* Am2_hi  = (u16*)alloc((size_t)640*KTOT*2);
  u16* Am2_lo  = (u16*)alloc((size_t)640*KTOT*2);
  float* mask  = (float*)alloc((size_t)65536*576*4);
  float* flowlr= (float*)alloc((size_t)65536*2*4);
  (void)ws_size; (void)in_sizes; (void)n_in; (void)out_size;

  // zero padded buffers (borders must be 0; ws is poisoned with 0xAA)
  hipMemsetAsync(feat_hi, 0, NPAD*2, stream);
  hipMemsetAsync(feat_lo, 0, NPAD*2, stream);
  hipMemsetAsync(h_pad,  0, NPAD*4, stream);
  hipMemsetAsync(hm_hi,  0, NPAD*2, stream);
  hipMemsetAsync(hm_lo,  0, NPAD*2, stream);

  repack_feat<<<dim3(1024, 4), 256, 0, stream>>>(feat, feat_hi, feat_lo);
  repack_w<<<(256*KTOT + 255)/256, 256, 0, stream>>>(w_f1, A1_hi,  A1_lo,  256, 256);
  repack_w<<<(256*KTOT + 255)/256, 256, 0, stream>>>(w_m1, Am1_hi, Am1_lo, 256, 256);
  repack_w<<<(640*KTOT + 255)/256, 256, 0, stream>>>(w_m2, Am2_hi, Am2_lo, 576, 640);

  conv_gemm<<<dim3(512, 2), 256, 0, stream>>>(A1_hi,  A1_lo,  feat_hi, feat_lo, b_f1,
                                              h_pad, nullptr, nullptr, 0);
  conv_gemm<<<dim3(512, 2), 256, 0, stream>>>(Am1_hi, Am1_lo, feat_hi, feat_lo, b_m1,
                                              nullptr, hm_hi, hm_lo, 1);
  conv_gemm<<<dim3(512, 5), 256, 0, stream>>>(Am2_hi, Am2_lo, hm_hi, hm_lo, b_m2,
                                              mask, nullptr, nullptr, 2);
  conv_f2<<<1024, 256, 0, stream>>>(h_pad, w_f2, b_f2, flowlr);
  fuse_up<<<16384, 256, 0, stream>>>(mask, flowlr, img, bwarp, out);
}

// Round 3
// 1231.781 us; speedup vs baseline: 1.0684x; 1.0684x over previous
//
#include <hip/hip_runtime.h>
#include <cstdint>

typedef unsigned short u16;
typedef __bf16 bf8 __attribute__((ext_vector_type(8)));
typedef float f4 __attribute__((ext_vector_type(4)));
typedef u16 u16x4 __attribute__((ext_vector_type(4)));

#define NB 16
#define CH 256
#define HH 64
#define HP 66
#define KTOT 2304
#define SCALE (1.0f/48.0f)

// output offsets (floats) in d_out: out(16,3,512,512), flow, delta_flow, flow
#define OFF1 12582912
#define OFF2 20971520
#define OFF3 29360128

__device__ __forceinline__ unsigned bf16_rn(unsigned u) {
  return (u + 0x7fffu + ((u >> 16) & 1u)) >> 16;
}
__device__ __forceinline__ void split2(float x, u16 &h, u16 &l) {
  unsigned u = __float_as_uint(x);
  unsigned hb = bf16_rn(u);
  float hf = __uint_as_float(hb << 16);
  unsigned lb = bf16_rn(__float_as_uint(x - hf));
  h = (u16)hb; l = (u16)lb;
}

// async global->LDS, 16B per lane; lds pointer must be wave-uniform
__device__ __forceinline__ void g2l16(const void* g, void* l) {
  __builtin_amdgcn_global_load_lds(
      (__attribute__((address_space(1))) void*)(uintptr_t)g,
      (__attribute__((address_space(3))) void*)(uint32_t)(uintptr_t)l,
      16, 0, 0);
}

// ---------------- zero only the halo borders of the 5 padded buffers
// seg: n in [0,16), r in [0,260): y=0 row, y=65 row, x=0 col, x=65 col
__global__ void zero_halo(u16* __restrict__ b0, u16* __restrict__ b1,
                          u16* __restrict__ b2, u16* __restrict__ b3,
                          float* __restrict__ f0) {
  int seg = blockIdx.x;
  int n = seg / 260, r = seg - n*260;
  int y, x;
  if (r < 66)       { y = 0;       x = r; }
  else if (r < 132) { y = 65;      x = r - 66; }
  else if (r < 196) { y = r - 131; x = 0; }
  else              { y = r - 195; x = 65; }
  size_t base = (((size_t)n*HP + y)*HP + x)*CH + threadIdx.x*4;
  const u16x4 z16 = {0,0,0,0};
  const f4 z32 = {0.f,0.f,0.f,0.f};
  *(u16x4*)(b0 + base) = z16;
  *(u16x4*)(b1 + base) = z16;
  *(u16x4*)(b2 + base) = z16;
  *(u16x4*)(b3 + base) = z16;
  *(f4*)(f0 + base) = z32;
}

// ---------------- repack features: NCHW fp32 -> padded [n][66][66][ci] bf16 hi/lo
__global__ void repack_feat(const float* __restrict__ f, u16* __restrict__ hi,
                            u16* __restrict__ lo) {
  __shared__ float t[64][65];
  int ny = blockIdx.x; int n = ny >> 6, y = ny & 63;
  int ci0 = blockIdx.y << 6;
  int tid = threadIdx.x;
  int a = tid >> 6, bl = tid & 63;
  const float* src = f + (((size_t)n*CH + ci0)*HH + y)*HH;
  #pragma unroll
  for (int i = 0; i < 16; i++) {
    int ci = i*4 + a;
    t[ci][bl] = src[(size_t)ci*4096 + bl];
  }
  __syncthreads();
  size_t base = (((size_t)n*HP + (y+1))*HP + 1)*CH + ci0;
  #pragma unroll
  for (int i = 0; i < 16; i++) {
    int x = i*4 + a;
    float v = t[bl][x];
    u16 hv, lv; split2(v, hv, lv);
    hi[base + (size_t)x*CH + bl] = hv;
    lo[base + (size_t)x*CH + bl] = lv;
  }
}

// ---------------- repack weights: (Cout,256,3,3) -> A[co][t*256+ci] * 1/48, hi/lo
__global__ void repack_w(const float* __restrict__ w, u16* __restrict__ hi,
                         u16* __restrict__ lo, int Cout, int CoutPad) {
  int e = blockIdx.x*256 + threadIdx.x;
  if (e >= CoutPad*KTOT) return;
  int co = e / KTOT; int k = e - co*KTOT;
  int t = k >> 8, ci = k & 255;
  float v = 0.f;
  if (co < Cout) v = w[((size_t)co*CH + ci)*9 + t] * SCALE;
  u16 hv, lv; split2(v, hv, lv);
  hi[e] = hv; lo[e] = lv;
}

// ---------------- split-bf16 implicit-GEMM conv. 128x128 tile, BK=64.
// mode 0: h_pad fp32 relu(+bias)   mode 1: hm hi/lo bf16 relu(+bias)
// mode 2: mask fp32 (+bias), co<576
// flat grid 8*64*MB; XCD-aware swizzle: xcd=g&7, mb innermost per XCD so the
// MB sharers of each B tile are co-resident on one XCD (B reuse in L2).
__global__ __launch_bounds__(256, 2) void conv_gemm(
    const u16* __restrict__ Ahi, const u16* __restrict__ Alo,
    const u16* __restrict__ Bhi, const u16* __restrict__ Blo,
    const float* __restrict__ bias,
    float* __restrict__ outF, u16* __restrict__ outHi, u16* __restrict__ outLo,
    int mode, int MB) {
  __shared__ u16 AsHi[8192], AsLo[8192], BsHi[8192], BsLo[8192];
  const int tid = threadIdx.x;
  const int wave = tid >> 6;
  const int lane = tid & 63;
  int gidx = blockIdx.x;
  int xcd = gidx & 7, s = gidx >> 3;
  int cbl = s / MB;
  int mb = s - cbl*MB;
  int cb = xcd*64 + cbl;
  const int col0 = cb << 7;
  const int n = col0 >> 12;
  const int y0 = (col0 >> 6) & 63;

  // staging decomposition: seg(16 of 1KB) = wave*4+it; lane covers col=seg*8+(lane>>3),
  // 16B k-slot l=lane&7 holds swizzled k-segment g = l ^ (col&7)
  const int l8 = lane & 7;
  const int r8 = lane >> 3;
  const int gsg = l8 ^ r8;

  int aBase[4], bBase[4], segOf[4];
  #pragma unroll
  for (int it = 0; it < 4; ++it) {
    int seg = wave*4 + it;
    segOf[it] = seg*512;          // u16 elements = 1KB
    int rl = seg*8 + r8;          // rowLocal (A: co) / colLocal (B)
    aBase[it] = (mb*128 + rl)*KTOT + gsg*8;
    int yy = y0 + (rl >> 6);
    int xx = rl & 63;
    bBase[it] = ((n*HP + yy)*HP + xx)*CH + gsg*8;
  }

  const f4 zero = {0.f, 0.f, 0.f, 0.f};
  f4 acc[4][4];
  #pragma unroll
  for (int i = 0; i < 4; i++)
    #pragma unroll
    for (int j = 0; j < 4; j++) acc[i][j] = zero;

  const int wm = (wave >> 1) << 6;
  const int wn = (wave & 1) << 6;
  const int r16 = lane & 15;
  const int kg = lane >> 4;
  const int sw = lane & 7;

  for (int kc = 0; kc < 36; ++kc) {
    int t = kc >> 2;
    int ci0 = (kc & 3) << 6;
    int dy = t / 3;
    int dx = t - dy*3;
    int bOff = (dy*HP + dx)*CH + ci0;
    int aOff = kc << 6;
    #pragma unroll
    for (int it = 0; it < 4; ++it) {
      g2l16(Ahi + aBase[it] + aOff, AsHi + segOf[it]);
      g2l16(Alo + aBase[it] + aOff, AsLo + segOf[it]);
      g2l16(Bhi + bBase[it] + bOff, BsHi + segOf[it]);
      g2l16(Blo + bBase[it] + bOff, BsLo + segOf[it]);
    }
    __syncthreads();
    #pragma unroll
    for (int ks = 0; ks < 2; ++ks) {
      int slot = ((ks << 2) + kg) ^ sw;
      bf8 ahi[4], alo[4], bhi[4], blo[4];
      #pragma unroll
      for (int mi = 0; mi < 4; ++mi) {
        int idx = (wm + mi*16 + r16)*64 + slot*8;
        ahi[mi] = *(const bf8*)(AsHi + idx);
        alo[mi] = *(const bf8*)(AsLo + idx);
      }
      #pragma unroll
      for (int ni = 0; ni < 4; ++ni) {
        int idx = (wn + ni*16 + r16)*64 + slot*8;
        bhi[ni] = *(const bf8*)(BsHi + idx);
        blo[ni] = *(const bf8*)(BsLo + idx);
      }
      #pragma unroll
      for (int mi = 0; mi < 4; ++mi)
        #pragma unroll
        for (int ni = 0; ni < 4; ++ni) {
          acc[mi][ni] = __builtin_amdgcn_mfma_f32_16x16x32_bf16(ahi[mi], bhi[ni], acc[mi][ni], 0, 0, 0);
          acc[mi][ni] = __builtin_amdgcn_mfma_f32_16x16x32_bf16(ahi[mi], blo[ni], acc[mi][ni], 0, 0, 0);
          acc[mi][ni] = __builtin_amdgcn_mfma_f32_16x16x32_bf16(alo[mi], bhi[ni], acc[mi][ni], 0, 0, 0);
        }
    }
    __syncthreads();
  }

  // epilogue: C/D layout col=lane&15, row=(lane>>4)*4+reg  (row = co, col = spatial)
  const int g4 = kg << 2;
  #pragma unroll
  for (int mi = 0; mi < 4; ++mi) {
    int coB = mb*128 + wm + mi*16 + g4;
    bool valid = (mode != 2) || (coB < 576);
    f4 bv = zero;
    if (valid) bv = *(const f4*)(bias + coB);
    #pragma unroll
    for (int ni = 0; ni < 4; ++ni) {
      int col = col0 + wn + ni*16 + r16;
      f4 v = acc[mi][ni];
      #pragma unroll
      for (int q = 0; q < 4; q++) v[q] += bv[q];
      if (mode == 2) {
        if (valid) *(f4*)(outF + (size_t)col*576 + coB) = v;
      } else {
        #pragma unroll
        for (int q = 0; q < 4; q++) v[q] = fmaxf(v[q], 0.f);
        int nn = col >> 12, yy = (col >> 6) & 63, xx = col & 63;
        size_t addr = (((size_t)nn*HP + yy + 1)*HP + xx + 1)*CH + coB;
        if (mode == 0) {
          *(f4*)(outF + addr) = v;
        } else {
          u16x4 hv, lv;
          #pragma unroll
          for (int q = 0; q < 4; q++) { u16 a_, b_; split2(v[q], a_, b_); hv[q] = a_; lv[q] = b_; }
          *(u16x4*)(outHi + addr) = hv;
          *(u16x4*)(outLo + addr) = lv;
        }
      }
    }
  }
}

// ---------------- conv_f2: fp32 direct 256->2 from padded h
__global__ __launch_bounds__(256) void conv_f2(const float* __restrict__ hpad,
    const float* __restrict__ w2, const float* __restrict__ b2,
    float* __restrict__ flow) {
  __shared__ float ws[2*KTOT];
  int tid = threadIdx.x;
  for (int i = tid; i < 2*KTOT; i += 256) {
    int c = i / KTOT; int r = i - c*KTOT;
    int t = r >> 8, ci = r & 255;
    ws[i] = w2[((size_t)c*CH + ci)*9 + t] * SCALE;
  }
  __syncthreads();
  int ny = blockIdx.x; int n = ny >> 6, y = ny & 63;
  int wv = tid >> 6, lane = tid & 63;
  for (int p = 0; p < 16; p++) {
    int x = wv*16 + p;
    float s0 = 0.f, s1 = 0.f;
    #pragma unroll
    for (int t = 0; t < 9; t++) {
      int dy = t / 3, dx = t - dy*3;
      const float* hb = hpad + (((size_t)n*HP + y + dy)*HP + x + dx)*CH;
      const float* wa = ws + t*256;
      const float* wb = ws + KTOT + t*256;
      #pragma unroll
      for (int j = 0; j < 4; j++) {
        int ci = j*64 + lane;
        float v = hb[ci];
        s0 = fmaf(v, wa[ci], s0);
        s1 = fmaf(v, wb[ci], s1);
      }
    }
    #pragma unroll
    for (int o = 32; o; o >>= 1) { s0 += __shfl_xor(s0, o); s1 += __shfl_xor(s1, o); }
    if (lane == 0) {
      size_t col = (size_t)n*4096 + y*64 + x;
      flow[col*2]   = s0 + b2[0];
      flow[col*2+1] = s1 + b2[1];
    }
  }
}

// ---------------- fused: softmax(9) + convex upsample + grid + affine + bilinear sample
__global__ __launch_bounds__(256) void fuse_up(const float* __restrict__ mask,
    const float* __restrict__ flowlr, const float* __restrict__ img,
    const float* __restrict__ bwarp, float* __restrict__ out) {
  __shared__ float ms[4][576];
  __shared__ float fp[4][9][2];
  int tid = threadIdx.x;
  int cell = tid >> 6, lane = tid & 63;
  int b = blockIdx.x;
  int n = b >> 10;
  int h = (b >> 4) & 63;
  int w = ((b & 15) << 2) + cell;
  size_t col = (size_t)n*4096 + h*64 + w;
  #pragma unroll
  for (int r = 0; r < 9; r++) ms[cell][r*64 + lane] = mask[col*576 + r*64 + lane];
  if (lane < 18) {
    int k = lane >> 1, c = lane & 1;
    int hh = h + (k/3) - 1, ww = w + (k - (k/3)*3) - 1;
    float v = 0.f;
    if (hh >= 0 && hh < 64 && ww >= 0 && ww < 64)
      v = flowlr[(((size_t)n*4096) + hh*64 + ww)*2 + c];
    fp[cell][k][c] = 8.f * v;
  }
  __syncthreads();
  int u = lane >> 3, v = lane & 7;
  float mk[9]; float mx = -1e30f;
  #pragma unroll
  for (int k = 0; k < 9; k++) { mk[k] = ms[cell][k*64 + u*8 + v]; mx = fmaxf(mx, mk[k]); }
  float den = 0.f;
  #pragma unroll
  for (int k = 0; k < 9; k++) { mk[k] = __expf(mk[k] - mx); den += mk[k]; }
  float dxf = 0.f, dyf = 0.f;
  #pragma unroll
  for (int k = 0; k < 9; k++) { dxf += mk[k]*fp[cell][k][0]; dyf += mk[k]*fp[cell][k][1]; }
  dxf /= den; dyf /= den;
  int Y = h*8 + u, X = w*8 + v;
  float gx = (X + 0.5f)*(1.f/256.f) - 1.f;
  float gy = (Y + 0.5f)*(1.f/256.f) - 1.f;
  float fx = gx + dxf, fy = gy + dyf;
  const float* B = bwarp + n*6;
  float ax = B[0]*fx + B[1]*fy + B[2];
  float ay = B[3]*fx + B[4]*fy + B[5];
  size_t pix = (((size_t)n*512) + Y)*512 + X;
  *(float2*)(out + OFF1 + pix*2) = make_float2(ax, ay);
  *(float2*)(out + OFF2 + pix*2) = make_float2(dxf, dyf);
  *(float2*)(out + OFF3 + pix*2) = make_float2(ax, ay);
  float xs  = fminf(fmaxf((ax + 1.f)*256.f - 0.5f, 0.f), 511.f);
  float ysf = fminf(fmaxf((ay + 1.f)*256.f - 0.5f, 0.f), 511.f);
  float x0f = floorf(xs), y0f = floorf(ysf);
  int x0 = (int)x0f, y0 = (int)y0f;
  int x1 = min(x0 + 1, 511), y1 = min(y0 + 1, 511);
  float wx = xs - x0f, wy = ysf - y0f;
  #pragma unroll
  for (int c = 0; c < 3; c++) {
    const float* ip = img + ((size_t)(n*3 + c) << 18);
    float g00 = ip[y0*512 + x0], g01 = ip[y0*512 + x1];
    float g10 = ip[y1*512 + x0], g11 = ip[y1*512 + x1];
    float r = g00*(1.f-wx)*(1.f-wy) + g01*wx*(1.f-wy)
            + g10*(1.f-wx)*wy + g11*wx*wy;
    out[(((size_t)(n*3 + c))*512 + Y)*512 + X] = r;
  }
}

extern "C" void kernel_launch(void* const* d_in, const int* in_sizes, int n_in,
                              void* d_out, int out_size, void* d_ws, size_t ws_size,
                              hipStream_t stream) {
  const float* img   = (const float*)d_in[0];
  const float* feat  = (const float*)d_in[1];
  const float* bwarp = (const float*)d_in[2];
  const float* w_f1  = (const float*)d_in[3];
  const float* b_f1  = (const float*)d_in[4];
  const float* w_f2  = (const float*)d_in[5];
  const float* b_f2  = (const float*)d_in[6];
  const float* w_m1  = (const float*)d_in[7];
  const float* b_m1  = (const float*)d_in[8];
  const float* w_m2  = (const float*)d_in[9];
  const float* b_m2  = (const float*)d_in[10];
  float* out = (float*)d_out;

  char* ws = (char*)d_ws;
  size_t off = 0;
  auto alloc = [&](size_t bytes) -> char* {
    char* p = ws + off; off += (bytes + 255) & ~(size_t)255; return p;
  };
  const size_t NPAD = (size_t)NB*HP*HP*CH;   // 17,842,176
  u16* feat_hi = (u16*)alloc(NPAD*2);
  u16* feat_lo = (u16*)alloc(NPAD*2);
  float* h_pad = (float*)alloc(NPAD*4);
  u16* hm_hi   = (u16*)alloc(NPAD*2);
  u16* hm_lo   = (u16*)alloc(NPAD*2);
  u16* A1_hi   = (u16*)alloc((size_t)256*KTOT*2);
  u16* A1_lo   = (u16*)alloc((size_t)256*KTOT*2);
  u16* Am1_hi  = (u16*)alloc((size_t)256*KTOT*2);
  u16* Am1_lo  = (u16*)alloc((size_t)256*KTOT*2);
  u16* Am2_hi  = (u16*)alloc((size_t)640*KTOT*2);
  u16* Am2_lo  = (u16*)alloc((size_t)640*KTOT*2);
  float* mask  = (float*)alloc((size_t)65536*576*4);
  float* flowlr= (float*)alloc((size_t)65536*2*4);
  (void)ws_size; (void)in_sizes; (void)n_in; (void)out_size;

  // zero only halo borders (interiors are fully overwritten by repack/epilogues)
  zero_halo<<<NB*260, 64, 0, stream>>>(feat_hi, feat_lo, hm_hi, hm_lo, h_pad);

  repack_feat<<<dim3(1024, 4), 256, 0, stream>>>(feat, feat_hi, feat_lo);
  repack_w<<<(256*KTOT + 255)/256, 256, 0, stream>>>(w_f1, A1_hi,  A1_lo,  256, 256);
  repack_w<<<(256*KTOT + 255)/256, 256, 0, stream>>>(w_m1, Am1_hi, Am1_lo, 256, 256);
  repack_w<<<(640*KTOT + 255)/256, 256, 0, stream>>>(w_m2, Am2_hi, Am2_lo, 576, 640);

  conv_gemm<<<1024, 256, 0, stream>>>(A1_hi,  A1_lo,  feat_hi, feat_lo, b_f1,
                                      h_pad, nullptr, nullptr, 0, 2);
  conv_gemm<<<1024, 256, 0, stream>>>(Am1_hi, Am1_lo, feat_hi, feat_lo, b_m1,
                                      nullptr, hm_hi, hm_lo, 1, 2);
  conv_gemm<<<2560, 256, 0, stream>>>(Am2_hi, Am2_lo, hm_hi, hm_lo, b_m2,
                                      mask, nullptr, nullptr, 2, 5);
  conv_f2<<<1024, 256, 0, stream>>>(h_pad, w_f2, b_f2, flowlr);
  fuse_up<<<16384, 256, 0, stream>>>(mask, flowlr, img, bwarp, out);
}